// Round 4
// baseline (638.869 us; speedup 1.0000x reference)
//
#include <hip/hip_runtime.h>
#include <hip/hip_bf16.h>

// Problem constants
#define S_LEN 8192
#define NH    16
#define HD    128      // head dim
#define HID   2048     // hidden
#define NQKV  6144     // fused QKV output width
#define CHUNK 12
#define MP    12
#define CTX   24
#define POS   13
#define NBLK  683      // ceil(8192/12)

typedef short bf16x8 __attribute__((ext_vector_type(8)));
typedef float f32x4  __attribute__((ext_vector_type(4)));
typedef unsigned short u16;
typedef u16 u16x8 __attribute__((ext_vector_type(8)));
typedef u16 u16x4 __attribute__((ext_vector_type(4)));

#define MFMA16 __builtin_amdgcn_mfma_f32_16x16x32_bf16

__device__ __forceinline__ void glds16(const u16* g, u16* l) {
  __builtin_amdgcn_global_load_lds(
      (__attribute__((address_space(1))) void*)(void*)g,
      (__attribute__((address_space(3))) void*)l, 16, 0, 0);
}

__device__ __forceinline__ u16 f2b(float f) {
  __hip_bfloat16 h = __float2bfloat16(f);
  return *(u16*)&h;
}

// ---------------------------------------------------------------- convert
__global__ __launch_bounds__(256) void f32_to_bf16(const float* __restrict__ in,
                                                   u16* __restrict__ out, int n) {
  int i = (blockIdx.x * 256 + threadIdx.x) * 4;
  if (i < n) {
    float4 v = *(const float4*)(in + i);
    u16x4 o = {f2b(v.x), f2b(v.y), f2b(v.z), f2b(v.w)};
    *(u16x4*)(out + i) = o;
  }
}

// ---------------------------------------------------------------- transpose x4
__global__ __launch_bounds__(256) void transpose4(const float* __restrict__ W0,
                                                  const float* __restrict__ W1,
                                                  const float* __restrict__ W2,
                                                  const float* __restrict__ W3,
                                                  u16* __restrict__ out) {
  __shared__ u16 t[64][72];
  const int z = blockIdx.z;
  const float* in = (z == 0) ? W0 : (z == 1) ? W1 : (z == 2) ? W2 : W3;
  u16* dst = out + (size_t)z * HID * HID;
  const int bx = blockIdx.x * 64, by = blockIdx.y * 64;
  const int x = threadIdx.x & 63;
  const int y4 = threadIdx.x >> 6;
  for (int r = y4; r < 64; r += 4)
    t[r][x] = f2b(in[(size_t)(by + r) * HID + bx + x]);
  __syncthreads();
  for (int r = y4; r < 64; r += 4)
    dst[(size_t)(bx + r) * HID + by + x] = t[x][r];
}

// ---------------------------------------------------------------- q scale
__global__ void qscale_kernel(const float* __restrict__ pds, float* __restrict__ qs) {
  int d = threadIdx.x;
  float x = pds[d];
  float sp = log1pf(expf(x));
  qs[d] = 0.08838834764831845f * 1.4426950408889634f * sp;
}

// ---------------------------------------------------------------- rel_k
__global__ __launch_bounds__(256) void relk_atomic(const float* __restrict__ pos,
                                                   const float* __restrict__ Wrel,
                                                   float* __restrict__ RELF) {
  const int col = blockIdx.x * 256 + threadIdx.x;
  const int c0 = blockIdx.y * 256;
  float acc[POS] = {};
  for (int c = c0; c < c0 + 256; ++c) {
    float wv = Wrel[(size_t)c * HID + col];
#pragma unroll
    for (int p = 0; p < POS; ++p) acc[p] += pos[p * HID + c] * wv;
  }
#pragma unroll
  for (int p = 0; p < POS; ++p) atomicAdd(&RELF[p * HID + col], acc[p]);
}

__global__ __launch_bounds__(256) void relk_cvt(const float* __restrict__ RELF,
                                                u16* __restrict__ REL) {
  int i = blockIdx.x * 256 + threadIdx.x;
  if (i < POS * HID) REL[i] = f2b(RELF[i]);
}

// ---------------------------------------------------------------- GEMM
// (unchanged from round 2: BK=64 as two BK=32 sub-tiles, glds width-16)
__global__ __launch_bounds__(256) void gemm_bt(const u16* __restrict__ A,
                                               const u16* __restrict__ Bt,
                                               u16* __restrict__ Co,
                                               float* __restrict__ Cf,
                                               const float* __restrict__ colscale,
                                               int NN, int csLimit) {
  __shared__ u16 lA[2][128 * 32];
  __shared__ u16 lB[2][128 * 32];
  const int tid = threadIdx.x;
  const int lane = tid & 63, w = tid >> 6;
  const int quad = lane >> 4, l = lane & 15;
  const int bm = blockIdx.x * 128, bn = blockIdx.y * 128;
  const int wm = (w >> 1) * 64, wn = (w & 1) * 64;

  f32x4 acc[4][4] = {};

  for (int kt = 0; kt < HID; kt += 64) {
#pragma unroll
    for (int r = 0; r < 2; ++r) {
      int o = w * 1024 + r * 4096 + lane * 16;
      int m = o >> 6;
      int ke = (o & 63) >> 1;
      const u16* ga = A + (size_t)(bm + m) * HID + kt + ke;
      const u16* gb = Bt + (size_t)(bn + m) * HID + kt + ke;
      u16* dA = lA[0] + w * 512 + r * 2048;
      u16* dB = lB[0] + w * 512 + r * 2048;
      glds16(ga, dA);
      glds16(ga + 32, dA + 128 * 32);
      glds16(gb, dB);
      glds16(gb + 32, dB + 128 * 32);
    }
    __syncthreads();

#pragma unroll
    for (int kk = 0; kk < 2; ++kk) {
      bf16x8 af[4], bfr[4];
#pragma unroll
      for (int i = 0; i < 4; ++i)
        af[i] = *(const bf16x8*)(lA[kk] + (wm + i * 16 + l) * 32 + quad * 8);
#pragma unroll
      for (int j = 0; j < 4; ++j)
        bfr[j] = *(const bf16x8*)(lB[kk] + (wn + j * 16 + l) * 32 + quad * 8);
#pragma unroll
      for (int i = 0; i < 4; ++i)
#pragma unroll
        for (int j = 0; j < 4; ++j)
          acc[i][j] = MFMA16(af[i], bfr[j], acc[i][j], 0, 0, 0);
    }
    __syncthreads();
  }

#pragma unroll
  for (int i = 0; i < 4; ++i)
#pragma unroll
    for (int j = 0; j < 4; ++j)
#pragma unroll
      for (int r = 0; r < 4; ++r) {
        int row = bm + wm + i * 16 + quad * 4 + r;
        int col = bn + wn + j * 16 + l;
        float v = acc[i][j][r];
        if (colscale && col < csLimit) v *= colscale[col & (HD - 1)];
        if (Cf) Cf[(size_t)row * NN + col] = v;
        else    Co[(size_t)row * NN + col] = f2b(v);
      }
}

// ---------------------------------------------------------------- attention
// v2: 1 wave per (n,h). Q/K/rel MFMA fragments loaded DIRECTLY from global
// (A-frag of Q and B-frag of K are contiguous 16B row segments — no staging).
// Only V round-trips LDS (transpose for PV B-fragment). LDS 11.5 KB ->
// ~14 waves/CU (was 11 at 13.8 KB). One barrier total.
__global__ __launch_bounds__(64) void attn_kernel(const u16* __restrict__ qkv,
                                                  const u16* __restrict__ relg,
                                                  u16* __restrict__ og) {
  __shared__ u16 vt[128 * 40]; // [d][ctx] stride 40 (80B: 2-way alias = free)
  __shared__ u16 ps[16 * 40];  // P in A-layout [c][ctx]
  const int n = blockIdx.x, h = blockIdx.y;
  const int lane = threadIdx.x;
  const int quad = lane >> 4, l = lane & 15;
  const int base = n * CHUNK;
  const u16x8 zero8 = {0, 0, 0, 0, 0, 0, 0, 0};

  const u16* qg = qkv + h * HD;
  const u16* kg = qkv + 2048 + h * HD;
  const u16* vg = qkv + 4096 + h * HD;

  // V load (vector 16B) -> LDS transpose writes
  const int vctx = lane & 31, vdc = lane >> 5; // + 2*i on vdc per iter
#pragma unroll
  for (int i = 0; i < 8; ++i) {
    int dc = vdc + 2 * i;
    int s = base + vctx - MP;
    u16x8 v = (vctx < CTX && s >= 0 && s < S_LEN)
                  ? *(const u16x8*)(vg + (size_t)s * NQKV + dc * 8)
                  : zero8;
#pragma unroll
    for (int jj = 0; jj < 8; ++jj) vt[(dc * 8 + jj) * 40 + vctx] = v[jj];
  }

  // direct-global fragment rows
  const int sq = min(base + l, S_LEN - 1);        // Q row (clamped; tail rows unused)
  const int sk0 = base + l - MP;                  // K ctx = l
  const int sk1 = base + 4 + l;                   // K ctx = 16+l
  const bool k0v = (sk0 >= 0) && (sk0 < S_LEN);
  const bool k1v = (l < CTX - 16) && (sk1 < S_LEN);
  const u16* qrow = qg + (size_t)sq * NQKV;
  const u16* k0row = kg + (size_t)(k0v ? sk0 : 0) * NQKV;
  const u16* k1row = kg + (size_t)(k1v ? sk1 : 0) * NQKV;
  const u16* rrow = relg + (size_t)(l < POS ? l : 0) * HID + h * HD;

  f32x4 ac0 = {0, 0, 0, 0}, ac1 = {0, 0, 0, 0}, bd = {0, 0, 0, 0};
#pragma unroll
  for (int t = 0; t < 4; ++t) {
    int d0 = t * 32 + quad * 8;
    bf16x8 aQ = *(const bf16x8*)(qrow + d0);
    bf16x8 bK0 = k0v ? *(const bf16x8*)(k0row + d0) : (bf16x8)zero8;
    bf16x8 bK1 = k1v ? *(const bf16x8*)(k1row + d0) : (bf16x8)zero8;
    bf16x8 bR = (l < POS) ? *(const bf16x8*)(rrow + d0) : (bf16x8)zero8;
    ac0 = MFMA16(aQ, bK0, ac0, 0, 0, 0);
    ac1 = MFMA16(aQ, bK1, ac1, 0, 0, 0);
    bd = MFMA16(aQ, bR, bd, 0, 0, 0);
  }

  // softcap + softmax (C/D layout: row c = quad*4+r, col ctx = l / 16+l)
  float p0[4], p1[4];
#pragma unroll
  for (int r = 0; r < 4; ++r) {
    int c = quad * 4 + r;
    int pi0 = l - c;
    int pi1 = 16 + l - c;
    int sp0 = pi0 < 0 ? 0 : (pi0 > 15 ? 15 : pi0);
    int sp1 = pi1 < 0 ? 0 : (pi1 > 15 ? 15 : pi1);
    float b0 = __shfl(bd[r], quad * 16 + sp0, 64);
    float b1 = __shfl(bd[r], quad * 16 + sp1, 64);
    b0 = (pi0 >= 0 && pi0 < POS) ? b0 : 0.0f;
    b1 = (pi1 >= 0 && pi1 < POS) ? b1 : 0.0f;
    float s0 = tanhf((ac0[r] + b0) * (1.0f / 50.0f)) * 50.0f;
    float s1 = tanhf((ac1[r] + b1) * (1.0f / 50.0f)) * 50.0f;
    bool v1 = (l < (CTX - 16));
    if (!v1) s1 = -1e30f;
    float mx = fmaxf(s0, s1);
#pragma unroll
    for (int d = 1; d < 16; d <<= 1) mx = fmaxf(mx, __shfl_xor(mx, d, 64));
    float e0 = __expf(s0 - mx);
    float e1 = v1 ? __expf(s1 - mx) : 0.0f;
    float sm = e0 + e1;
#pragma unroll
    for (int d = 1; d < 16; d <<= 1) sm += __shfl_xor(sm, d, 64);
    float inv = 1.0f / sm;
    p0[r] = e0 * inv;
    p1[r] = e1 * inv;
  }
#pragma unroll
  for (int r = 0; r < 4; ++r) {
    int c = quad * 4 + r;
    ps[c * 40 + l] = f2b(p0[r]);
    ps[c * 40 + 16 + l] = f2b(p1[r]); // ctx 16..31; zero where invalid
  }
  __syncthreads();

  // PV: out[c][d] = sum_ctx P[c][ctx] * V[ctx][d]
  bf16x8 aP = *(const bf16x8*)(ps + l * 40 + quad * 8);
#pragma unroll
  for (int nt = 0; nt < 8; ++nt) {
    bf16x8 bV = *(const bf16x8*)(vt + (nt * 16 + l) * 40 + quad * 8);
    f32x4 o = {0, 0, 0, 0};
    o = MFMA16(aP, bV, o, 0, 0, 0);
#pragma unroll
    for (int r = 0; r < 4; ++r) {
      int c = quad * 4 + r;
      int s = base + c;
      if (c < CHUNK && s < S_LEN)
        og[(size_t)s * HID + h * HD + nt * 16 + l] = f2b(o[r]);
    }
  }
}

// ---------------------------------------------------------------- launch
extern "C" void kernel_launch(void* const* d_in, const int* in_sizes, int n_in,
                              void* d_out, int out_size, void* d_ws, size_t ws_size,
                              hipStream_t stream) {
  const float* x = (const float*)d_in[0];
  const float* pos = (const float*)d_in[1];
  const float* Wq = (const float*)d_in[2];
  const float* Wk = (const float*)d_in[3];
  const float* Wv = (const float*)d_in[4];
  const float* Wrel = (const float*)d_in[5];
  const float* Wpost = (const float*)d_in[6];
  const float* pds = (const float*)d_in[7];

  char* ws = (char*)d_ws;
  u16* WT  = (u16*)(ws);                      // 4 x [2048][2048] bf16 = 32 MB
  u16* xb  = (u16*)(ws + 33554432);           // [8192][2048] bf16 = 32 MB
  u16* AO  = xb;                              // alias: xb dead after QKV GEMM
  u16* QKV = (u16*)(ws + 67108864);           // [8192][6144] bf16 = 96 MB
  float* RELF = (float*)(ws + 167772160);     // [13][2048] f32
  u16* REL = (u16*)(ws + 167878656);          // [13][2048] bf16
  float* QS = (float*)(ws + 167931904);       // [128] f32

  const int NX = S_LEN * HID;
  f32_to_bf16<<<NX / 4 / 256, 256, 0, stream>>>(x, xb, NX);

  transpose4<<<dim3(32, 32, 4), 256, 0, stream>>>(Wq, Wk, Wv, Wpost, WT);
  qscale_kernel<<<1, 128, 0, stream>>>(pds, QS);

  hipMemsetAsync(RELF, 0, POS * HID * sizeof(float), stream);
  relk_atomic<<<dim3(8, 8), 256, 0, stream>>>(pos, Wrel, RELF);
  relk_cvt<<<(POS * HID + 255) / 256, 256, 0, stream>>>(RELF, REL);

  // fused QKV GEMM: Bt rows 0..6143 of WT; colscale on Q columns only
  gemm_bt<<<dim3(64, 48), 256, 0, stream>>>(xb, WT, QKV, nullptr, QS, NQKV, 2048);

  attn_kernel<<<dim3(NBLK, NH), 64, 0, stream>>>(QKV, REL, AO);

  // post GEMM: Bt = transposed Wpost (slab 3), f32 out
  gemm_bt<<<dim3(64, 16), 256, 0, stream>>>(AO, WT + (size_t)3 * HID * HID,
                                            nullptr, (float*)d_out, nullptr, HID, 0);
}